// Round 22
// baseline (150.356 us; speedup 1.0000x reference)
//
#include <hip/hip_runtime.h>
#include <math.h>
#include <stdint.h>

typedef __attribute__((ext_vector_type(8))) short short8;
typedef __attribute__((ext_vector_type(4))) float f32x4;

__device__ __forceinline__ uint32_t cvt_pk_bf16(float lo, float hi) {
  uint32_t r;
  asm("v_cvt_pk_bf16_f32 %0, %1, %2" : "=v"(r) : "v"(lo), "v"(hi));
  return r;
}

// inverse-distance weight; invalid j has cx=cy=1e30 -> d2 overflows to inf
// -> rcp(inf)=0, so invalid columns contribute exactly 0.
__device__ __forceinline__ float wfun(float hx, float hy, float cx, float cy) {
  float dx = hx - cx, dy = hy - cy;
  float d = __builtin_amdgcn_sqrtf(fmaf(dx, dx, dy * dy));
  return __builtin_amdgcn_rcpf(d + 1e-4f);
}

// ---------------------------------------------------------------------------
// Kernel 1: WgT[a][k] = bf16(Wg[k][a])  (verified)
__global__ __launch_bounds__(256) void k_prep_w(
    const float* __restrict__ Wg, uint16_t* __restrict__ WgT, int F, int A) {
  int idx = blockIdx.x * 256 + threadIdx.x;
  int a = idx % A;
  int k0 = (idx / A) * 8;
  if (k0 >= F) return;
  float f[8];
  #pragma unroll
  for (int e = 0; e < 8; ++e) f[e] = Wg[(size_t)(k0 + e) * A + a];
  uint4 v;
  v.x = cvt_pk_bf16(f[0], f[1]);
  v.y = cvt_pk_bf16(f[2], f[3]);
  v.z = cvt_pk_bf16(f[4], f[5]);
  v.w = cvt_pk_bf16(f[6], f[7]);
  *(uint4*)(WgT + (size_t)a * F + k0) = v;
}

// ---------------------------------------------------------------------------
// Kernel 2 (FUSED targets + head): round-21-verified body widened to 512
// threads = 8 waves = 2(wm) x 4(wn), nf=4 -> 2 waves/SIMD (was 1,
// latency-bound). Block still owns its whole tgt2 tile (no r20-style write
// split) and reads the same WgT volume. W_h side-dot on wn==0 waves.
__global__ __launch_bounds__(512) void k_fused_tgt_head(
    const float* __restrict__ batch, const uint16_t* __restrict__ WgT,
    const float* __restrict__ bg, const float* __restrict__ W_h,
    const float* __restrict__ b_h, const float* __restrict__ xywh,
    uint16_t* __restrict__ tgt2, float* __restrict__ hp_out,
    float* __restrict__ hx, float* __restrict__ hy,
    float* __restrict__ validf, float2* __restrict__ cxy,
    int S, int F, int A) {
  int t = threadIdx.x;
  int lane = t & 63, wid = t >> 6;     // 8 waves
  int wm = wid >> 2, wn = wid & 3;     // 2 row-groups x 4 col-groups
  int i0 = blockIdx.x * 32;
  int row = i0 + wm * 16 + (lane & 15);
  int kch = lane >> 4;
  const float* ab = batch + (size_t)row * F + kch * 8;
  int ncol0 = wn * 64 + (lane & 15);
  const uint16_t* bb = WgT + (size_t)ncol0 * F + kch * 8;

  f32x4 acc[4] = {};
  float wh0 = 0.f, wh1 = 0.f;
  float4 a0 = *(const float4*)(ab);
  float4 a1 = *(const float4*)(ab + 4);
  short8 bf[4];
  #pragma unroll
  for (int nf = 0; nf < 4; ++nf)
    bf[nf] = *(const short8*)(bb + (size_t)nf * 16 * F);

  for (int k0 = 0; k0 < F; k0 += 32) {
    int kn = (k0 + 32 < F) ? k0 + 32 : 0;  // wrap prefetch (harmless)
    float4 na0 = *(const float4*)(ab + kn);
    float4 na1 = *(const float4*)(ab + kn + 4);
    short8 nbf[4];
    #pragma unroll
    for (int nf = 0; nf < 4; ++nf)
      nbf[nf] = *(const short8*)(bb + kn + (size_t)nf * 16 * F);

    if (wn == 0) {  // fp32 W_h side-dot on this lane's 8 k's (exact path)
      const float* whp = W_h + 2 * (k0 + kch * 8);
      float4 h0 = *(const float4*)(whp);
      float4 h1 = *(const float4*)(whp + 4);
      float4 h2 = *(const float4*)(whp + 8);
      float4 h3 = *(const float4*)(whp + 12);
      wh0 += a0.x*h0.x + a0.y*h0.z + a0.z*h1.x + a0.w*h1.z
           + a1.x*h2.x + a1.y*h2.z + a1.z*h3.x + a1.w*h3.z;
      wh1 += a0.x*h0.y + a0.y*h0.w + a0.z*h1.y + a0.w*h1.w
           + a1.x*h2.y + a1.y*h2.w + a1.z*h3.y + a1.w*h3.w;
    }

    union { short8 s; uint32_t u[4]; } af;
    af.u[0] = cvt_pk_bf16(a0.x, a0.y);
    af.u[1] = cvt_pk_bf16(a0.z, a0.w);
    af.u[2] = cvt_pk_bf16(a1.x, a1.y);
    af.u[3] = cvt_pk_bf16(a1.z, a1.w);
    #pragma unroll
    for (int nf = 0; nf < 4; ++nf)
      acc[nf] = __builtin_amdgcn_mfma_f32_16x16x32_bf16(af.s, bf[nf], acc[nf], 0, 0, 0);
    a0 = na0; a1 = na1;
    #pragma unroll
    for (int nf = 0; nf < 4; ++nf) bf[nf] = nbf[nf];
  }

  int jb = blockIdx.x;
  int rloc = wm * 16 + (lane >> 4) * 4;   // row within tile, mult of 4
  #pragma unroll
  for (int nf = 0; nf < 4; ++nf) {
    int col = ncol0 + nf * 16;
    float b = bg[col];
    float o0 = fmaxf(acc[nf][0] + b, 0.f);
    float o1 = fmaxf(acc[nf][1] + b, 0.f);
    float o2 = fmaxf(acc[nf][2] + b, 0.f);
    float o3 = fmaxf(acc[nf][3] + b, 0.f);
    uint2 pk;
    pk.x = cvt_pk_bf16(o0, o1);
    pk.y = cvt_pk_bf16(o2, o3);
    *(uint2*)(tgt2 + ((size_t)jb * A + col) * 32 + rloc) = pk;
  }

  // head epilogue: reduce over the 4 kch groups, write per-row values
  if (wn == 0) {
    wh0 += __shfl_xor(wh0, 16, 64);
    wh0 += __shfl_xor(wh0, 32, 64);
    wh1 += __shfl_xor(wh1, 16, 64);
    wh1 += __shfl_xor(wh1, 32, 64);
    if (lane < 16) {
      int r = i0 + wm * 16 + lane;
      float hp0 = tanhf(wh0 + b_h[0]);
      float hp1 = tanhf(wh1 + b_h[1]);
      float4 xy = ((const float4*)xywh)[r];
      hp_out[2 * r] = hp0;
      hp_out[2 * r + 1] = hp1;
      hx[r] = hp0 * xy.z * 4.0f + xy.x;  // SIGMA_X = 4
      hy[r] = hp1 * xy.w * 1.0f + xy.y;  // SIGMA_Y = 1
      bool v = (xy.x + xy.y + xy.z + xy.w >= 1e-8f);
      validf[r] = v ? 1.0f : 0.0f;
      cxy[r] = v ? make_float2(xy.x, xy.y) : make_float2(1e30f, 1e30f);
    }
  }
}

// ---------------------------------------------------------------------------
// Kernel 3: out = rownorm(W) @ targets. Round-16 verified kernel (102.5 us),
// byte-identical: 1024 thr = 2(kg) x 2(wm) x 4(wn); 1-barrier dbuf pipeline;
// dedup w-gen via Af (2 wfun/thread/step); reg-staged stride-40 Bt.
__global__ __launch_bounds__(1024, 4) void k_gather_v16(
    const uint16_t* __restrict__ tgt2, const float2* __restrict__ cxy,
    const float* __restrict__ hx, const float* __restrict__ hy,
    const float* __restrict__ validf, float* __restrict__ out, int S, int A) {
  __shared__ uint16_t Bt[2][2][256][40];   // [dbuf][kg][col][40hw]   80 KB
  __shared__ uint32_t Af[2][2][2][64][4];  // [dbuf][kg][wm][lane][s]  8 KB
  __shared__ float comb[32][260];          // kg=1 partial acc        33.3 KB
  __shared__ float rs_l[2][32][16];        // [kg][row][jp]            4 KB
  __shared__ float scale_s[32];

  int t = threadIdx.x;
  int lane = t & 63, wid = t >> 6;
  int kg = wid >> 3;                 // 0..1 (j-half)
  int sub = wid & 7;
  int wm = sub >> 2, wn = sub & 3;   // 2M x 4N
  int i0 = blockIdx.x * 32;
  int kch = lane >> 4;
  int n0 = wn * 64 + (lane & 15);    // col 0..255
  int NT = (S >> 1) / 32;            // 128 tiles per K-group
  const size_t TSTRIDE = (size_t)A * 32;
  const int COLS = 40;

  // ---- writer role (all 1024 threads): (row wr, j-pair wjp) of kg's tile
  int u = t & 511;
  int wr = u & 31;                   // 0..31
  int wjp = u >> 5;                  // 0..15
  float hx_w = hx[i0 + wr], hy_w = hy[i0 + wr];
  uint32_t* afw0 = &Af[0][kg][wr >> 4][(wr & 15) | ((wjp >> 2) << 4)][wjp & 3];
  uint32_t* afw1 = &Af[1][kg][wr >> 4][(wr & 15) | ((wjp >> 2) << 4)][wjp & 3];
  const float2* gC = cxy + (size_t)kg * (S >> 1) + 2 * wjp;  // + tile*32

  // ---- staging role: 32 B (2 x uint4) of kg's tile per step
  int scol = u >> 1;                 // 0..255
  int skw = u & 1;                   // 0..1 (32-B half of the 64-B column)
  const uint16_t* gB0 = tgt2 + (size_t)(kg * NT) * TSTRIDE
                        + (size_t)scol * 32 + skw * 16;

  f32x4 acc[4] = {};
  float rs = 0.f;

  // ---- prologue: w(tile0) + B(tile0) into buffer 0; preload c(tile1)
  {
    float4 c0 = *(const float4*)(gC);
    float wA = wfun(hx_w, hy_w, c0.x, c0.y);
    float wB = wfun(hx_w, hy_w, c0.z, c0.w);
    rs += wA + wB;
    *afw0 = cvt_pk_bf16(wA, wB);
    uint4 ga = *(const uint4*)(gB0);
    uint4 gb = *(const uint4*)(gB0 + 8);
    *(uint4*)&Bt[0][kg][scol][skw * 16] = ga;
    *(uint4*)&Bt[0][kg][scol][skw * 16 + 8] = gb;
  }
  float4 ccur = *(const float4*)(gC + 32);   // c for tile 1
  __syncthreads();

  for (int ts = 0; ts < NT; ++ts) {
    int nxt = (ts & 1) ^ 1;
    int tn = (ts + 1 < NT) ? ts + 1 : 0;     // next tile (wrap harmless)
    int tf = (ts + 2 < NT) ? ts + 2 : 0;     // c two ahead

    // issue next-tile B loads + c(ts+2) load (latency hidden by compute)
    const uint16_t* bp = gB0 + (size_t)tn * TSTRIDE;
    uint4 ga = *(const uint4*)(bp);
    uint4 gb = *(const uint4*)(bp + 8);
    float4 cfut = *(const float4*)(gC + (size_t)tf * 32);

    // read A-frag + B-frags for current tile
    const uint32_t* afp = &Af[ts & 1][kg][wm][lane][0];
    short8 afr = *(const short8*)afp;
    const uint16_t* br = &Bt[ts & 1][kg][n0][kch * 8];
    short8 b0 = *(const short8*)(br);
    short8 b1 = *(const short8*)(br + 16 * COLS);
    short8 b2 = *(const short8*)(br + 32 * COLS);
    short8 b3 = *(const short8*)(br + 48 * COLS);

    acc[0] = __builtin_amdgcn_mfma_f32_16x16x32_bf16(afr, b0, acc[0], 0, 0, 0);
    acc[1] = __builtin_amdgcn_mfma_f32_16x16x32_bf16(afr, b1, acc[1], 0, 0, 0);
    acc[2] = __builtin_amdgcn_mfma_f32_16x16x32_bf16(afr, b2, acc[2], 0, 0, 0);
    acc[3] = __builtin_amdgcn_mfma_f32_16x16x32_bf16(afr, b3, acc[3], 0, 0, 0);

    // w-gen for tile ts+1 (rs gated off on the wrapped last step)
    float wA = wfun(hx_w, hy_w, ccur.x, ccur.y);
    float wB = wfun(hx_w, hy_w, ccur.z, ccur.w);
    float g = (ts + 1 < NT) ? 1.f : 0.f;
    rs = fmaf(g, wA + wB, rs);
    uint32_t pk = cvt_pk_bf16(wA, wB);
    uint32_t* afw = nxt ? afw1 : afw0;
    *afw = pk;

    // write staged B to the other buffer
    *(uint4*)&Bt[nxt][kg][scol][skw * 16] = ga;
    *(uint4*)&Bt[nxt][kg][scol][skw * 16 + 8] = gb;
    ccur = cfut;
    __syncthreads();
  }

  // ---- rowsum: per-thread (kg,row,jp) partials -> LDS reduce
  rs_l[kg][wr][wjp] = rs;

  // kg=1 publishes its partial acc
  if (kg == 1) {
    int mre = wm * 16 + (lane >> 4) * 4;
    #pragma unroll
    for (int r = 0; r < 4; ++r) {
      comb[mre + r][n0]      = acc[0][r];
      comb[mre + r][n0 + 16] = acc[1][r];
      comb[mre + r][n0 + 32] = acc[2][r];
      comb[mre + r][n0 + 48] = acc[3][r];
    }
  }
  __syncthreads();
  if (t < 32) {
    float r = 0.f;
    #pragma unroll
    for (int jp = 0; jp < 16; ++jp) r += rs_l[0][t][jp] + rs_l[1][t][jp];
    float v = validf[i0 + t];
    scale_s[t] = (v > 0.f) ? 1.0f / fmaxf(r, 1e-30f) : 0.f;
  }
  __syncthreads();
  if (kg == 0) {
    int mre = wm * 16 + (lane >> 4) * 4;
    #pragma unroll
    for (int r = 0; r < 4; ++r) {
      float s = scale_s[mre + r];
      size_t base = (size_t)(i0 + mre + r) * A;
      out[base + n0]      = (acc[0][r] + comb[mre + r][n0]) * s;
      out[base + n0 + 16] = (acc[1][r] + comb[mre + r][n0 + 16]) * s;
      out[base + n0 + 32] = (acc[2][r] + comb[mre + r][n0 + 32]) * s;
      out[base + n0 + 48] = (acc[3][r] + comb[mre + r][n0 + 48]) * s;
    }
  }
}

extern "C" void kernel_launch(void* const* d_in, const int* in_sizes, int n_in,
                              void* d_out, int out_size, void* d_ws, size_t ws_size,
                              hipStream_t stream) {
  // inputs: 0 batch[S,F] 1 xywh[S,4] 2 OW 3 OH 4 actor_weights[S] 5 avg_pos[S,2]
  //         6 W_h[F,2] 7 b_h[2] 8 W_g[F,A] 9 b_g[A] 10 num_person
  const float* batch = (const float*)d_in[0];
  const float* xywh  = (const float*)d_in[1];
  const float* W_h   = (const float*)d_in[6];
  const float* b_h   = (const float*)d_in[7];
  const float* W_g   = (const float*)d_in[8];
  const float* b_g   = (const float*)d_in[9];
  int S = in_sizes[4];
  int F = in_sizes[0] / S;
  int A = in_sizes[9];

  float* out    = (float*)d_out;
  float* out_tw = out;                        // [S,A]
  float* out_hp = out + (size_t)S * A;        // [S,2]

  // workspace: tgt2 bf16 [S/32][A][32], WgT bf16 [A][F], hx/hy/validf, cxy
  uint16_t* tgt2 = (uint16_t*)d_ws;
  uint16_t* WgT  = tgt2 + (size_t)A * S;
  float* hxv = (float*)(WgT + (size_t)A * F);
  float* hyv = hxv + S;
  float* vfv = hyv + S;
  float2* cxyv = (float2*)(vfv + S);

  k_prep_w<<<dim3((A * F / 8 + 255) / 256), 256, 0, stream>>>(W_g, WgT, F, A);
  k_fused_tgt_head<<<dim3(S / 32), 512, 0, stream>>>(batch, WgT, b_g, W_h, b_h,
                                                     xywh, tgt2, out_hp, hxv,
                                                     hyv, vfv, cxyv, S, F, A);
  k_gather_v16<<<dim3(S / 32), 1024, 0, stream>>>(tgt2, cxyv, hxv, hyv, vfv,
                                                  out_tw, S, A);
}

// Round 23
// 131.810 us; speedup vs baseline: 1.1407x; 1.1407x over previous
//
#include <hip/hip_runtime.h>
#include <math.h>
#include <stdint.h>

typedef __attribute__((ext_vector_type(8))) short short8;
typedef __attribute__((ext_vector_type(4))) float f32x4;

__device__ __forceinline__ uint32_t cvt_pk_bf16(float lo, float hi) {
  uint32_t r;
  asm("v_cvt_pk_bf16_f32 %0, %1, %2" : "=v"(r) : "v"(lo), "v"(hi));
  return r;
}

// inverse-distance weight; invalid j has cx=cy=1e30 -> d2 overflows to inf
// -> rcp(inf)=0, so invalid columns contribute exactly 0.
__device__ __forceinline__ float wfun(float hx, float hy, float cx, float cy) {
  float dx = hx - cx, dy = hy - cy;
  float d = __builtin_amdgcn_sqrtf(fmaf(dx, dx, dy * dy));
  return __builtin_amdgcn_rcpf(d + 1e-4f);
}

// ---------------------------------------------------------------------------
// Kernel 1: WgT[a][k] = bf16(Wg[k][a])  (verified)
__global__ __launch_bounds__(256) void k_prep_w(
    const float* __restrict__ Wg, uint16_t* __restrict__ WgT, int F, int A) {
  int idx = blockIdx.x * 256 + threadIdx.x;
  int a = idx % A;
  int k0 = (idx / A) * 8;
  if (k0 >= F) return;
  float f[8];
  #pragma unroll
  for (int e = 0; e < 8; ++e) f[e] = Wg[(size_t)(k0 + e) * A + a];
  uint4 v;
  v.x = cvt_pk_bf16(f[0], f[1]);
  v.y = cvt_pk_bf16(f[2], f[3]);
  v.z = cvt_pk_bf16(f[4], f[5]);
  v.w = cvt_pk_bf16(f[6], f[7]);
  *(uint4*)(WgT + (size_t)a * F + k0) = v;
}

// ---------------------------------------------------------------------------
// Kernel 2 (FUSED targets + head): ROUND-21 VERIFIED version (256 threads,
// 4 waves = 2wm x 2wn, nf=8; W_h side-dot on wn==0 waves).
__global__ __launch_bounds__(256) void k_fused_tgt_head(
    const float* __restrict__ batch, const uint16_t* __restrict__ WgT,
    const float* __restrict__ bg, const float* __restrict__ W_h,
    const float* __restrict__ b_h, const float* __restrict__ xywh,
    uint16_t* __restrict__ tgt2, float* __restrict__ hp_out,
    float* __restrict__ hx, float* __restrict__ hy,
    float* __restrict__ validf, float2* __restrict__ cxy,
    int S, int F, int A) {
  int t = threadIdx.x;
  int lane = t & 63, wid = t >> 6;
  int wm = wid >> 1, wn = wid & 1;
  int i0 = blockIdx.x * 32;
  int row = i0 + wm * 16 + (lane & 15);
  int kch = lane >> 4;
  const float* ab = batch + (size_t)row * F + kch * 8;
  int ncol0 = wn * 128 + (lane & 15);
  const uint16_t* bb = WgT + (size_t)ncol0 * F + kch * 8;

  f32x4 acc[8] = {};
  float wh0 = 0.f, wh1 = 0.f;
  float4 a0 = *(const float4*)(ab);
  float4 a1 = *(const float4*)(ab + 4);
  short8 bf[8];
  #pragma unroll
  for (int nf = 0; nf < 8; ++nf)
    bf[nf] = *(const short8*)(bb + (size_t)nf * 16 * F);

  for (int k0 = 0; k0 < F; k0 += 32) {
    int kn = (k0 + 32 < F) ? k0 + 32 : 0;  // wrap prefetch (harmless)
    float4 na0 = *(const float4*)(ab + kn);
    float4 na1 = *(const float4*)(ab + kn + 4);
    short8 nbf[8];
    #pragma unroll
    for (int nf = 0; nf < 8; ++nf)
      nbf[nf] = *(const short8*)(bb + kn + (size_t)nf * 16 * F);

    if (wn == 0) {  // fp32 W_h side-dot on this lane's 8 k's (exact path)
      const float* whp = W_h + 2 * (k0 + kch * 8);
      float4 h0 = *(const float4*)(whp);
      float4 h1 = *(const float4*)(whp + 4);
      float4 h2 = *(const float4*)(whp + 8);
      float4 h3 = *(const float4*)(whp + 12);
      wh0 += a0.x*h0.x + a0.y*h0.z + a0.z*h1.x + a0.w*h1.z
           + a1.x*h2.x + a1.y*h2.z + a1.z*h3.x + a1.w*h3.z;
      wh1 += a0.x*h0.y + a0.y*h0.w + a0.z*h1.y + a0.w*h1.w
           + a1.x*h2.y + a1.y*h2.w + a1.z*h3.y + a1.w*h3.w;
    }

    union { short8 s; uint32_t u[4]; } af;
    af.u[0] = cvt_pk_bf16(a0.x, a0.y);
    af.u[1] = cvt_pk_bf16(a0.z, a0.w);
    af.u[2] = cvt_pk_bf16(a1.x, a1.y);
    af.u[3] = cvt_pk_bf16(a1.z, a1.w);
    #pragma unroll
    for (int nf = 0; nf < 8; ++nf)
      acc[nf] = __builtin_amdgcn_mfma_f32_16x16x32_bf16(af.s, bf[nf], acc[nf], 0, 0, 0);
    a0 = na0; a1 = na1;
    #pragma unroll
    for (int nf = 0; nf < 8; ++nf) bf[nf] = nbf[nf];
  }

  int jb = blockIdx.x;
  int rloc = wm * 16 + (lane >> 4) * 4;   // row within tile, mult of 4
  #pragma unroll
  for (int nf = 0; nf < 8; ++nf) {
    int col = ncol0 + nf * 16;
    float b = bg[col];
    float o0 = fmaxf(acc[nf][0] + b, 0.f);
    float o1 = fmaxf(acc[nf][1] + b, 0.f);
    float o2 = fmaxf(acc[nf][2] + b, 0.f);
    float o3 = fmaxf(acc[nf][3] + b, 0.f);
    uint2 pk;
    pk.x = cvt_pk_bf16(o0, o1);
    pk.y = cvt_pk_bf16(o2, o3);
    *(uint2*)(tgt2 + ((size_t)jb * A + col) * 32 + rloc) = pk;
  }

  // head epilogue: reduce over the 4 kch groups, write per-row values
  if (wn == 0) {
    wh0 += __shfl_xor(wh0, 16, 64);
    wh0 += __shfl_xor(wh0, 32, 64);
    wh1 += __shfl_xor(wh1, 16, 64);
    wh1 += __shfl_xor(wh1, 32, 64);
    if (lane < 16) {
      int r = i0 + wm * 16 + lane;
      float hp0 = tanhf(wh0 + b_h[0]);
      float hp1 = tanhf(wh1 + b_h[1]);
      float4 xy = ((const float4*)xywh)[r];
      hp_out[2 * r] = hp0;
      hp_out[2 * r + 1] = hp1;
      hx[r] = hp0 * xy.z * 4.0f + xy.x;  // SIGMA_X = 4
      hy[r] = hp1 * xy.w * 1.0f + xy.y;  // SIGMA_Y = 1
      bool v = (xy.x + xy.y + xy.z + xy.w >= 1e-8f);
      validf[r] = v ? 1.0f : 0.0f;
      cxy[r] = v ? make_float2(xy.x, xy.y) : make_float2(1e30f, 1e30f);
    }
  }
}

// ---------------------------------------------------------------------------
// Kernel 3: out = rownorm(W) @ targets.  BM=64 x BN=128, 1024 thr = 16 waves
// = 4(kg) x 2(wm) x 2(wn); each wave multiplies BOTH row-groups (2 Af + 4 B
// reads per 8 MFMA -> 1.25 LDS-instr/MFMA vs v16's 2.0). v16's verified
// 1-barrier dbuf pipeline; stride-40 Bt (aligned b128); v17's Af mapping
// (b64 writes, 2 slot-adjacent jp-pairs per h); round-robin comb epilogue.
__global__ __launch_bounds__(1024, 4) void k_gather_v20(
    const uint16_t* __restrict__ tgt2, const float2* __restrict__ cxy,
    const float* __restrict__ hx, const float* __restrict__ hy,
    const float* __restrict__ validf, float* __restrict__ out, int S, int A) {
  __shared__ uint16_t Bt[2][4][128][40];      // [buf][kg][col][40hw]   80 KB
  __shared__ uint32_t Af[2][4][2][2][64][4];  // [buf][kg][wm][rg][ln][s] 32 KB
  __shared__ float comb[64][132];             // round-robin partials  33.8 KB
  __shared__ float rs_l[4][64][4];            // [kg][row][z]            4 KB
  __shared__ float scale_s[64];

  int t = threadIdx.x;
  int lane = t & 63, wid = t >> 6;
  int kg = wid >> 2;                 // 0..3 (j-quarter)
  int sub = wid & 3;
  int wm = sub >> 1, wn = sub & 1;   // 2 x 2
  int colhalf = blockIdx.x;          // 0..1
  int i0 = blockIdx.y * 64;
  int kch = lane >> 4;
  int n0 = wn * 64 + (lane & 15);    // local col 0..127
  int NT = S / (4 * 32);             // 64 tiles per K-group
  const size_t TSTRIDE = (size_t)A * 32;
  const int COLS = 40;

  // ---- writer role: row wr (0..63), z selects 4 jp = {4h+m2, 4h+m2+1},
  // h in {h0, h0+2}. Af slot = jp&3, lane-high = jp>>2 = h. (v17 mapping)
  int wkg = t >> 8;                  // == kg
  int v = t & 255;
  int wr = v & 63;
  int z = v >> 6;                    // 0..3
  int m2 = (z & 1) * 2;              // slot base 0 or 2
  int h0 = z >> 1;                   // 0..1
  float hx_w = hx[i0 + wr], hy_w = hy[i0 + wr];
  int rgw = wr >> 5, wmw = (wr >> 4) & 1, rl = wr & 15;
  uint32_t* afA0 = &Af[0][wkg][wmw][rgw][rl | (h0 << 4)][m2];
  uint32_t* afB0 = &Af[0][wkg][wmw][rgw][rl | ((h0 + 2) << 4)][m2];
  uint32_t* afA1 = &Af[1][wkg][wmw][rgw][rl | (h0 << 4)][m2];
  uint32_t* afB1 = &Af[1][wkg][wmw][rgw][rl | ((h0 + 2) << 4)][m2];
  const float2* gC = cxy + (size_t)wkg * (S >> 2);
  int cOffA = 8 * h0 + 2 * m2;       // float2 units within tile
  int cOffB = cOffA + 16;

  // ---- staging role: 32 B (2 x uint4) per thread per step
  int scol = v >> 1;                 // 0..127
  int skw = v & 1;
  const uint16_t* gB0 = tgt2 + (size_t)(wkg * NT) * TSTRIDE
                        + (size_t)(colhalf * 128 + scol) * 32 + skw * 16;

  f32x4 acc0[4] = {};
  f32x4 acc1[4] = {};
  float rs = 0.f;

  // ---- prologue: stage tile 0 (B + w) into buffer 0
  {
    uint4 ga = *(const uint4*)(gB0);
    uint4 gb = *(const uint4*)(gB0 + 8);
    *(uint4*)&Bt[0][wkg][scol][skw * 16] = ga;
    *(uint4*)&Bt[0][wkg][scol][skw * 16 + 8] = gb;
    float4 ca = *(const float4*)(gC + cOffA);
    float4 cb = *(const float4*)(gC + cOffA + 2);
    float4 cc = *(const float4*)(gC + cOffB);
    float4 cd = *(const float4*)(gC + cOffB + 2);
    float w0 = wfun(hx_w, hy_w, ca.x, ca.y);
    float w1 = wfun(hx_w, hy_w, ca.z, ca.w);
    float w2 = wfun(hx_w, hy_w, cb.x, cb.y);
    float w3 = wfun(hx_w, hy_w, cb.z, cb.w);
    float w4 = wfun(hx_w, hy_w, cc.x, cc.y);
    float w5 = wfun(hx_w, hy_w, cc.z, cc.w);
    float w6 = wfun(hx_w, hy_w, cd.x, cd.y);
    float w7 = wfun(hx_w, hy_w, cd.z, cd.w);
    rs += ((w0 + w1) + (w2 + w3)) + ((w4 + w5) + (w6 + w7));
    uint2 pA = make_uint2(cvt_pk_bf16(w0, w1), cvt_pk_bf16(w2, w3));
    uint2 pB = make_uint2(cvt_pk_bf16(w4, w5), cvt_pk_bf16(w6, w7));
    *(uint2*)afA0 = pA;
    *(uint2*)afB0 = pB;
  }
  __syncthreads();

  for (int ts = 0; ts < NT; ++ts) {
    int cur = ts & 1, nxt = cur ^ 1;
    int tn = (ts + 1 < NT) ? ts + 1 : 0;   // next tile (wrap harmless)

    // issue next-tile loads (latency hidden under this tile's compute)
    const uint16_t* bp = gB0 + (size_t)tn * TSTRIDE;
    uint4 ga = *(const uint4*)(bp);
    uint4 gb = *(const uint4*)(bp + 8);
    const float2* cp = gC + (size_t)tn * 32;
    float4 ca = *(const float4*)(cp + cOffA);
    float4 cb = *(const float4*)(cp + cOffA + 2);
    float4 cc = *(const float4*)(cp + cOffB);
    float4 cd = *(const float4*)(cp + cOffB + 2);

    // read 2 A-frags + 4 B-frags; 8 MFMA
    short8 a0 = *(const short8*)&Af[cur][kg][wm][0][lane][0];
    short8 a1 = *(const short8*)&Af[cur][kg][wm][1][lane][0];
    const uint16_t* br = &Bt[cur][kg][n0][kch * 8];
    short8 b0 = *(const short8*)(br);
    short8 b1 = *(const short8*)(br + 16 * COLS);
    short8 b2 = *(const short8*)(br + 32 * COLS);
    short8 b3 = *(const short8*)(br + 48 * COLS);

    acc0[0] = __builtin_amdgcn_mfma_f32_16x16x32_bf16(a0, b0, acc0[0], 0, 0, 0);
    acc0[1] = __builtin_amdgcn_mfma_f32_16x16x32_bf16(a0, b1, acc0[1], 0, 0, 0);
    acc0[2] = __builtin_amdgcn_mfma_f32_16x16x32_bf16(a0, b2, acc0[2], 0, 0, 0);
    acc0[3] = __builtin_amdgcn_mfma_f32_16x16x32_bf16(a0, b3, acc0[3], 0, 0, 0);
    acc1[0] = __builtin_amdgcn_mfma_f32_16x16x32_bf16(a1, b0, acc1[0], 0, 0, 0);
    acc1[1] = __builtin_amdgcn_mfma_f32_16x16x32_bf16(a1, b1, acc1[1], 0, 0, 0);
    acc1[2] = __builtin_amdgcn_mfma_f32_16x16x32_bf16(a1, b2, acc1[2], 0, 0, 0);
    acc1[3] = __builtin_amdgcn_mfma_f32_16x16x32_bf16(a1, b3, acc1[3], 0, 0, 0);

    // w-gen for tile tn (rs gated off on the wrapped last step)
    float w0 = wfun(hx_w, hy_w, ca.x, ca.y);
    float w1 = wfun(hx_w, hy_w, ca.z, ca.w);
    float w2 = wfun(hx_w, hy_w, cb.x, cb.y);
    float w3 = wfun(hx_w, hy_w, cb.z, cb.w);
    float w4 = wfun(hx_w, hy_w, cc.x, cc.y);
    float w5 = wfun(hx_w, hy_w, cc.z, cc.w);
    float w6 = wfun(hx_w, hy_w, cd.x, cd.y);
    float w7 = wfun(hx_w, hy_w, cd.z, cd.w);
    float g = (ts + 1 < NT) ? 1.f : 0.f;
    rs = fmaf(g, ((w0 + w1) + (w2 + w3)) + ((w4 + w5) + (w6 + w7)), rs);
    uint2 pA = make_uint2(cvt_pk_bf16(w0, w1), cvt_pk_bf16(w2, w3));
    uint2 pB = make_uint2(cvt_pk_bf16(w4, w5), cvt_pk_bf16(w6, w7));
    *(uint2*)(nxt ? afA1 : afA0) = pA;
    *(uint2*)(nxt ? afB1 : afB0) = pB;

    // write staged B to the other buffer (its reads finished last iter)
    *(uint4*)&Bt[nxt][wkg][scol][skw * 16] = ga;
    *(uint4*)&Bt[nxt][wkg][scol][skw * 16 + 8] = gb;
    __syncthreads();
  }

  // ---- epilogue: rowsum + 3-round kg combine
  rs_l[wkg][wr][z] = rs;
  int rbase = (lane >> 4) * 4;

  if (kg == 1) {
    #pragma unroll
    for (int r = 0; r < 4; ++r) {
      int r0 = wm * 16 + rbase + r, r1 = 32 + r0;
      comb[r0][n0]      = acc0[0][r];
      comb[r0][n0 + 16] = acc0[1][r];
      comb[r0][n0 + 32] = acc0[2][r];
      comb[r0][n0 + 48] = acc0[3][r];
      comb[r1][n0]      = acc1[0][r];
      comb[r1][n0 + 16] = acc1[1][r];
      comb[r1][n0 + 32] = acc1[2][r];
      comb[r1][n0 + 48] = acc1[3][r];
    }
  }
  __syncthreads();
  if (t < 64) {
    float r = 0.f;
    #pragma unroll
    for (int k2 = 0; k2 < 4; ++k2)
      #pragma unroll
      for (int z2 = 0; z2 < 4; ++z2) r += rs_l[k2][t][z2];
    float fv = validf[i0 + t];
    scale_s[t] = (fv > 0.f) ? 1.0f / fmaxf(r, 1e-30f) : 0.f;
  }
  if (kg == 0) {
    #pragma unroll
    for (int r = 0; r < 4; ++r) {
      int r0 = wm * 16 + rbase + r, r1 = 32 + r0;
      acc0[0][r] += comb[r0][n0];
      acc0[1][r] += comb[r0][n0 + 16];
      acc0[2][r] += comb[r0][n0 + 32];
      acc0[3][r] += comb[r0][n0 + 48];
      acc1[0][r] += comb[r1][n0];
      acc1[1][r] += comb[r1][n0 + 16];
      acc1[2][r] += comb[r1][n0 + 32];
      acc1[3][r] += comb[r1][n0 + 48];
    }
  }
  __syncthreads();
  if (kg == 2) {
    #pragma unroll
    for (int r = 0; r < 4; ++r) {
      int r0 = wm * 16 + rbase + r, r1 = 32 + r0;
      comb[r0][n0]      = acc0[0][r];
      comb[r0][n0 + 16] = acc0[1][r];
      comb[r0][n0 + 32] = acc0[2][r];
      comb[r0][n0 + 48] = acc0[3][r];
      comb[r1][n0]      = acc1[0][r];
      comb[r1][n0 + 16] = acc1[1][r];
      comb[r1][n0 + 32] = acc1[2][r];
      comb[r1][n0 + 48] = acc1[3][r];
    }
  }
  __syncthreads();
  if (kg == 0) {
    #pragma unroll
    for (int r = 0; r < 4; ++r) {
      int r0 = wm * 16 + rbase + r, r1 = 32 + r0;
      acc0[0][r] += comb[r0][n0];
      acc0[1][r] += comb[r0][n0 + 16];
      acc0[2][r] += comb[r0][n0 + 32];
      acc0[3][r] += comb[r0][n0 + 48];
      acc1[0][r] += comb[r1][n0];
      acc1[1][r] += comb[r1][n0 + 16];
      acc1[2][r] += comb[r1][n0 + 32];
      acc1[3][r] += comb[r1][n0 + 48];
    }
  }
  __syncthreads();
  if (kg == 3) {
    #pragma unroll
    for (int r = 0; r < 4; ++r) {
      int r0 = wm * 16 + rbase + r, r1 = 32 + r0;
      comb[r0][n0]      = acc0[0][r];
      comb[r0][n0 + 16] = acc0[1][r];
      comb[r0][n0 + 32] = acc0[2][r];
      comb[r0][n0 + 48] = acc0[3][r];
      comb[r1][n0]      = acc1[0][r];
      comb[r1][n0 + 16] = acc1[1][r];
      comb[r1][n0 + 32] = acc1[2][r];
      comb[r1][n0 + 48] = acc1[3][r];
    }
  }
  __syncthreads();
  if (kg == 0) {
    int cb = colhalf * 128;
    #pragma unroll
    for (int r = 0; r < 4; ++r) {
      int r0 = wm * 16 + rbase + r, r1 = 32 + r0;
      float s0 = scale_s[r0], s1 = scale_s[r1];
      size_t b0o = (size_t)(i0 + r0) * A + cb;
      size_t b1o = (size_t)(i0 + r1) * A + cb;
      out[b0o + n0]      = (acc0[0][r] + comb[r0][n0]) * s0;
      out[b0o + n0 + 16] = (acc0[1][r] + comb[r0][n0 + 16]) * s0;
      out[b0o + n0 + 32] = (acc0[2][r] + comb[r0][n0 + 32]) * s0;
      out[b0o + n0 + 48] = (acc0[3][r] + comb[r0][n0 + 48]) * s0;
      out[b1o + n0]      = (acc1[0][r] + comb[r1][n0]) * s1;
      out[b1o + n0 + 16] = (acc1[1][r] + comb[r1][n0 + 16]) * s1;
      out[b1o + n0 + 32] = (acc1[2][r] + comb[r1][n0 + 32]) * s1;
      out[b1o + n0 + 48] = (acc1[3][r] + comb[r1][n0 + 48]) * s1;
    }
  }
}

extern "C" void kernel_launch(void* const* d_in, const int* in_sizes, int n_in,
                              void* d_out, int out_size, void* d_ws, size_t ws_size,
                              hipStream_t stream) {
  // inputs: 0 batch[S,F] 1 xywh[S,4] 2 OW 3 OH 4 actor_weights[S] 5 avg_pos[S,2]
  //         6 W_h[F,2] 7 b_h[2] 8 W_g[F,A] 9 b_g[A] 10 num_person
  const float* batch = (const float*)d_in[0];
  const float* xywh  = (const float*)d_in[1];
  const float* W_h   = (const float*)d_in[6];
  const float* b_h   = (const float*)d_in[7];
  const float* W_g   = (const float*)d_in[8];
  const float* b_g   = (const float*)d_in[9];
  int S = in_sizes[4];
  int F = in_sizes[0] / S;
  int A = in_sizes[9];

  float* out    = (float*)d_out;
  float* out_tw = out;                        // [S,A]
  float* out_hp = out + (size_t)S * A;        // [S,2]

  // workspace: tgt2 bf16 [S/32][A][32], WgT bf16 [A][F], hx/hy/validf, cxy
  uint16_t* tgt2 = (uint16_t*)d_ws;
  uint16_t* WgT  = tgt2 + (size_t)A * S;
  float* hxv = (float*)(WgT + (size_t)A * F);
  float* hyv = hxv + S;
  float* vfv = hyv + S;
  float2* cxyv = (float2*)(vfv + S);

  k_prep_w<<<dim3((A * F / 8 + 255) / 256), 256, 0, stream>>>(W_g, WgT, F, A);
  k_fused_tgt_head<<<dim3(S / 32), 256, 0, stream>>>(batch, WgT, b_g, W_h, b_h,
                                                     xywh, tgt2, out_hp, hxv,
                                                     hyv, vfv, cxyv, S, F, A);
  k_gather_v20<<<dim3(2, S / 64), 1024, 0, stream>>>(tgt2, cxyv, hxv, hyv, vfv,
                                                     out_tw, S, A);
}